// Round 11
// baseline (176.207 us; speedup 1.0000x reference)
//
#include <hip/hip_runtime.h>

#define N 4096
#define NBINS 10            // bins 0..9 accumulated; bin 10 analytic
#define BLOCK 256
#define NSLOTS 64           // spread-atomic slots, 64 B apart
#define GROUPS 4            // 4 groups of 4 float4 per lane (64 elems/lane)
#define GF4 4

// ===== DIAGNOSTIC ROUND =====
// The row kernel runs its main loop 3x: one real pass + two decoy passes over
// the same row (column-rotated, L2-resident, weighted by a runtime-opaque
// zero). Purpose: push the dispatch above the top-5 duration cutoff so we
// finally get VALUBusy/Occupancy/VGPR/FETCH for OUR kernel, and recover
// dur1 = dur3 - (total_new - 139.9). absmax unchanged (z == 0.0 exactly).

// Kernel A: cid recovery (validated R6-R9, absmax=0) + zero the slots and
// the opaque-zero flag (harness poisons ws with 0xAA).
__global__ __launch_bounds__(BLOCK) void fastap_cid_kernel(
    const float* __restrict__ labels, unsigned short* __restrict__ cid,
    float* __restrict__ slots, float* __restrict__ zflag)
{
    if (blockIdx.x == 0) {
        if (threadIdx.x < NSLOTS) slots[threadIdx.x * 16] = 0.f;
        if (threadIdx.x == 0) zflag[0] = 0.f;
    }
    const int lane = threadIdx.x & 63;
    const int wid  = (blockIdx.x * BLOCK + threadIdx.x) >> 6;
    #pragma unroll
    for (int rr = 0; rr < 4; ++rr) {
        const int row = wid * 4 + rr;
        const float4* l4 = (const float4*)(labels + (size_t)row * N);
        bool done = false;
        for (int r = 0; !done; ++r) {                // terminates at diagonal
            float4 v = l4[r * 64 + lane];
            bool any = (v.x > 0.5f) || (v.y > 0.5f) || (v.z > 0.5f) || (v.w > 0.5f);
            unsigned long long m = __ballot(any);
            if (m) {
                int fl = __builtin_ctzll(m);
                if (lane == fl) {
                    int e = (v.x > 0.5f) ? 0 : (v.y > 0.5f) ? 1 : (v.z > 0.5f) ? 2 : 3;
                    cid[row] = (unsigned short)(r * 256 + lane * 4 + e);
                }
                done = true;
            }
        }
    }
}

// one full row pass: rolling-prefetch loop + butterfly + AP epilogue.
// rot = float4-index rotation within the row (multiple of 64 keeps wave
// loads contiguous). Returns ap/Np (identical on all lanes).
__device__ __forceinline__ float row_pass(const float4* __restrict__ b4,
                                          int lane, unsigned mlo, unsigned mhi,
                                          float np, int rot)
{
    float hc_pos[NBINS], hc_all[NBINS];
    #pragma unroll
    for (int l = 0; l < NBINS; ++l) { hc_pos[l] = 0.f; hc_all[l] = 0.f; }

    float4 buf[2][GF4];
    #pragma unroll
    for (int i = 0; i < GF4; ++i)
        buf[0][i] = b4[(i * 64 + lane + rot) & (N / 4 - 1)];

    #pragma unroll
    for (int g = 0; g < GROUPS; ++g) {
        if (g + 1 < GROUPS) {   // rolling prefetch: only batch loads in loop
            #pragma unroll
            for (int i = 0; i < GF4; ++i)
                buf[(g + 1) & 1][i] =
                    b4[(((g + 1) * GF4 + i) * 64 + lane + rot) & (N / 4 - 1)];
        }
        const unsigned mw = (g < 2) ? mlo : mhi;
        #pragma unroll
        for (int i = 0; i < GF4; ++i) {
            #pragma unroll
            for (int e = 0; e < 4; ++e) {
                float x   = ((const float*)&buf[g & 1][i])[e];
                float lbl = (float)((mw >> ((g & 1) * 16 + i * 4 + e)) & 1u);
                float u = fmaf(5.f, x, -4.f);     // 1 - dist2/Delta
                #pragma unroll
                for (int l = 0; l < NBINS; ++l) {
                    float c = fminf(fmaxf(u + (float)l, 0.f), 1.f); // add+clamp
                    hc_pos[l] = fmaf(c, lbl, hc_pos[l]);
                    hc_all[l] += c;
                }
            }
        }
    }

    #pragma unroll
    for (int off = 1; off < 64; off <<= 1) {
        #pragma unroll
        for (int l = 0; l < NBINS; ++l) {
            hc_pos[l] += __shfl_xor(hc_pos[l], off, 64);
            hc_all[l] += __shfl_xor(hc_all[l], off, 64);
        }
    }

    float Hp_prev = 0.f, ap = 0.f;
    #pragma unroll
    for (int l = 0; l < NBINS; ++l) {
        float Hp = hc_pos[l];
        float Ha = hc_all[l];
        float hp = Hp - Hp_prev;
        if (Ha > 0.f) ap += hp * Hp / Ha;
        Hp_prev = Hp;
    }
    ap += (np - Hp_prev) * np * (1.f / (float)N);  // analytic bin 10
    return ap / np;                                 // np >= 1 (diagonal)
}

// Kernel B: one row per wave, no barriers; mask-register labels (R9).
// Pass 1 real (rot 0, HBM); passes 2-3 decoys (rot 256/512 float4s,
// L2-resident), weighted by opaque zero.
__global__ __launch_bounds__(BLOCK) void fastap_row_kernel(
    const float* __restrict__ batch, const unsigned short* __restrict__ cid,
    float* __restrict__ slots, const float* __restrict__ zflag)
{
    const int tid  = threadIdx.x;
    const int lane = tid & 63;
    const int row  = (blockIdx.x * BLOCK + tid) >> 6;   // global wave id

    const float4*  b4 = (const float4*)(batch + (size_t)row * N);
    const ushort4* c4 = (const ushort4*)cid;            // 8 KB, cache-hot
    const int myc = (int)cid[row];                      // wave-uniform
    const float z = zflag[0];                           // runtime 0.0 (opaque)

    // build per-lane 64-bit label mask (cid loads oldest in vmcnt order)
    ushort4 cv[16];
    #pragma unroll
    for (int j = 0; j < 16; ++j) cv[j] = c4[j * 64 + lane];

    unsigned mlo = 0u, mhi = 0u;
    #pragma unroll
    for (int j = 0; j < 8; ++j) {
        mlo |= ((int)cv[j].x == myc ? 1u : 0u) << (j * 4 + 0);
        mlo |= ((int)cv[j].y == myc ? 1u : 0u) << (j * 4 + 1);
        mlo |= ((int)cv[j].z == myc ? 1u : 0u) << (j * 4 + 2);
        mlo |= ((int)cv[j].w == myc ? 1u : 0u) << (j * 4 + 3);
    }
    #pragma unroll
    for (int j = 8; j < 16; ++j) {
        mhi |= ((int)cv[j].x == myc ? 1u : 0u) << ((j - 8) * 4 + 0);
        mhi |= ((int)cv[j].y == myc ? 1u : 0u) << ((j - 8) * 4 + 1);
        mhi |= ((int)cv[j].z == myc ? 1u : 0u) << ((j - 8) * 4 + 2);
        mhi |= ((int)cv[j].w == myc ? 1u : 0u) << ((j - 8) * 4 + 3);
    }

    float np = (float)(__popc(mlo) + __popc(mhi));
    #pragma unroll
    for (int off = 1; off < 64; off <<= 1) np += __shfl_xor(np, off, 64);

    float apR = row_pass(b4, lane, mlo, mhi, np, 0);     // real (HBM)
    float apA = row_pass(b4, lane, mlo, mhi, np, 256);   // decoy (L2-hot)
    float apB = row_pass(b4, lane, mlo, mhi, np, 512);   // decoy (L2-hot)

    if (lane == 0)
        atomicAdd(&slots[(row & (NSLOTS - 1)) * 16], apR + z * (apA + apB));
}

// Kernel C: one wave sums the 64 slots. loss = 1 - sum/N (all rows valid).
__global__ void fastap_finalize(const float* __restrict__ slots,
                                float* __restrict__ out)
{
    const int lane = threadIdx.x;
    float v = slots[lane * 16];
    #pragma unroll
    for (int off = 32; off > 0; off >>= 1)
        v += __shfl_down(v, off, 64);
    if (lane == 0) out[0] = 1.f - v * (1.f / (float)N);
}

extern "C" void kernel_launch(void* const* d_in, const int* in_sizes, int n_in,
                              void* d_out, int out_size, void* d_ws, size_t ws_size,
                              hipStream_t stream) {
    const float* batch  = (const float*)d_in[0];
    const float* labels = (const float*)d_in[1];
    unsigned short* cid = (unsigned short*)d_ws;            // 8 KB
    float* slots = (float*)((char*)d_ws + 8192);            // 4 KB
    float* zflag = (float*)((char*)d_ws + 8192 + 4096);     // opaque zero
    fastap_cid_kernel<<<N / (4 * 4), BLOCK, 0, stream>>>(labels, cid, slots, zflag);
    fastap_row_kernel<<<N / 4, BLOCK, 0, stream>>>(batch, cid, slots, zflag);
    fastap_finalize<<<1, 64, 0, stream>>>(slots, (float*)d_out);
}

// Round 12
// 142.291 us; speedup vs baseline: 1.2384x; 1.2384x over previous
//
#include <hip/hip_runtime.h>

#define N 4096
#define NBINS 10            // bins 0..9 accumulated; bin 10 analytic
#define BLOCK 256
#define NSLOTS 64           // spread-atomic slots, 64 B apart
#define GROUPS 4            // 4 groups of 4 float4 per lane (64 elems/lane)
#define GF4 4

typedef float float2v __attribute__((ext_vector_type(2)));

// R10 diagnostic found: the ~49us "wall" was rocprof inflation (~2.7x); real
// row kernel ~30us = ~18us execute + ~12us memory exposure; fixed harness
// ~103us. Cached decoy passes ran at the same per-pass cost as HBM passes ->
// NOT memory-bound; VALU-issue-bound at ~63% efficiency. This round: packed
// fp32 (v_pk_fma/add via float2 ext-vectors) halves bin-loop issue slots.

// Kernel A: cid recovery (validated R6-R10, absmax=0). cid[i] = column of
// first 1 in row i (ushort, 8 KB). Block 0 zeroes the atomic slots.
__global__ __launch_bounds__(BLOCK) void fastap_cid_kernel(
    const float* __restrict__ labels, unsigned short* __restrict__ cid,
    float* __restrict__ slots)
{
    if (blockIdx.x == 0 && threadIdx.x < NSLOTS)
        slots[threadIdx.x * 16] = 0.f;

    const int lane = threadIdx.x & 63;
    const int wid  = (blockIdx.x * BLOCK + threadIdx.x) >> 6;
    #pragma unroll
    for (int rr = 0; rr < 4; ++rr) {
        const int row = wid * 4 + rr;
        const float4* l4 = (const float4*)(labels + (size_t)row * N);
        bool done = false;
        for (int r = 0; !done; ++r) {                // terminates at diagonal
            float4 v = l4[r * 64 + lane];
            bool any = (v.x > 0.5f) || (v.y > 0.5f) || (v.z > 0.5f) || (v.w > 0.5f);
            unsigned long long m = __ballot(any);
            if (m) {
                int fl = __builtin_ctzll(m);
                if (lane == fl) {
                    int e = (v.x > 0.5f) ? 0 : (v.y > 0.5f) ? 1 : (v.z > 0.5f) ? 2 : 3;
                    cid[row] = (unsigned short)(r * 256 + lane * 4 + e);
                }
                done = true;
            }
        }
    }
}

// Kernel B: one row per wave, no barriers; mask-register labels (R9);
// rolling prefetch with ONLY batch loads in the loop (R9 vmcnt-order fix);
// NEW: float2-packed arithmetic — element pairs through v_pk_fma/v_pk_add,
// clamp via explicit fmed3; accumulators are float2 (even/odd partials,
// merged before the butterfly).
__global__ __launch_bounds__(BLOCK) void fastap_row_kernel(
    const float* __restrict__ batch, const unsigned short* __restrict__ cid,
    float* __restrict__ slots)
{
    const int tid  = threadIdx.x;
    const int lane = tid & 63;
    const int row  = (blockIdx.x * BLOCK + tid) >> 6;   // global wave id

    const float4*  b4 = (const float4*)(batch + (size_t)row * N);
    const ushort4* c4 = (const ushort4*)cid;            // 8 KB, cache-hot
    const int myc = (int)cid[row];                      // wave-uniform

    // --- prologue: cid loads FIRST (oldest in vmcnt order) ---
    ushort4 cv[16];
    #pragma unroll
    for (int j = 0; j < 16; ++j) cv[j] = c4[j * 64 + lane];

    // batch group-0 prefetch (youngest: outstanding during mask build)
    float4 buf[2][GF4];
    #pragma unroll
    for (int i = 0; i < GF4; ++i) buf[0][i] = b4[i * 64 + lane];

    // per-lane 64-bit label mask: bit (j*4+e) = (cid[j*256+lane*4+e] == myc)
    unsigned mlo = 0u, mhi = 0u;
    #pragma unroll
    for (int j = 0; j < 8; ++j) {
        mlo |= ((int)cv[j].x == myc ? 1u : 0u) << (j * 4 + 0);
        mlo |= ((int)cv[j].y == myc ? 1u : 0u) << (j * 4 + 1);
        mlo |= ((int)cv[j].z == myc ? 1u : 0u) << (j * 4 + 2);
        mlo |= ((int)cv[j].w == myc ? 1u : 0u) << (j * 4 + 3);
    }
    #pragma unroll
    for (int j = 8; j < 16; ++j) {
        mhi |= ((int)cv[j].x == myc ? 1u : 0u) << ((j - 8) * 4 + 0);
        mhi |= ((int)cv[j].y == myc ? 1u : 0u) << ((j - 8) * 4 + 1);
        mhi |= ((int)cv[j].z == myc ? 1u : 0u) << ((j - 8) * 4 + 2);
        mhi |= ((int)cv[j].w == myc ? 1u : 0u) << ((j - 8) * 4 + 3);
    }

    float2v hcp[NBINS], hca[NBINS];      // even/odd packed partials
    #pragma unroll
    for (int l = 0; l < NBINS; ++l) {
        hcp[l] = (float2v)(0.f);
        hca[l] = (float2v)(0.f);
    }

    #pragma unroll
    for (int g = 0; g < GROUPS; ++g) {
        if (g + 1 < GROUPS) {   // rolling prefetch: only batch loads in loop
            #pragma unroll
            for (int i = 0; i < GF4; ++i)
                buf[(g + 1) & 1][i] = b4[((g + 1) * GF4 + i) * 64 + lane];
        }
        const unsigned mw = (g < 2) ? mlo : mhi;
        #pragma unroll
        for (int i = 0; i < GF4; ++i) {
            const float4 f = buf[g & 1][i];
            #pragma unroll
            for (int p = 0; p < 2; ++p) {           // two pairs per float4
                float2v xv;
                xv.x = (p == 0) ? f.x : f.z;
                xv.y = (p == 0) ? f.y : f.w;
                // u = 5x - 4  -> v_pk_fma_f32
                float2v u = xv * 5.f + (-4.f);
                const unsigned bits = (mw >> ((g & 1) * 16 + i * 4 + 2 * p)) & 3u;
                float2v lbl;
                lbl.x = (float)(bits & 1u);
                lbl.y = (float)(bits >> 1);
                #pragma unroll
                for (int l = 0; l < NBINS; ++l) {
                    float2v c = u + (float)l;       // v_pk_add_f32
                    c.x = __builtin_amdgcn_fmed3f(c.x, 0.f, 1.f);
                    c.y = __builtin_amdgcn_fmed3f(c.y, 0.f, 1.f);
                    hcp[l] += c * lbl;              // v_pk_fma_f32
                    hca[l] += c;                    // v_pk_add_f32
                }
            }
        }
    }

    // merge even/odd partials, then butterfly 21 scalars across the wave
    float sp[NBINS], sa[NBINS];
    #pragma unroll
    for (int l = 0; l < NBINS; ++l) {
        sp[l] = hcp[l].x + hcp[l].y;
        sa[l] = hca[l].x + hca[l].y;
    }
    float np = (float)(__popc(mlo) + __popc(mhi));

    #pragma unroll
    for (int off = 1; off < 64; off <<= 1) {
        #pragma unroll
        for (int l = 0; l < NBINS; ++l) {
            sp[l] += __shfl_xor(sp[l], off, 64);
            sa[l] += __shfl_xor(sa[l], off, 64);
        }
        np += __shfl_xor(np, off, 64);
    }

    if (lane == 0) {
        float Hp_prev = 0.f, ap = 0.f;
        #pragma unroll
        for (int l = 0; l < NBINS; ++l) {
            float Hp = sp[l];
            float Ha = sa[l];
            float hp = Hp - Hp_prev;
            if (Ha > 0.f) ap += hp * Hp / Ha;
            Hp_prev = Hp;
        }
        float Np = np;                                 // >= 1 (diagonal)
        ap += (Np - Hp_prev) * Np * (1.f / (float)N);  // analytic bin 10
        atomicAdd(&slots[(row & (NSLOTS - 1)) * 16], ap / Np);
    }
}

// Kernel C: one wave sums the 64 slots. loss = 1 - sum/N (all rows valid).
__global__ void fastap_finalize(const float* __restrict__ slots,
                                float* __restrict__ out)
{
    const int lane = threadIdx.x;
    float v = slots[lane * 16];
    #pragma unroll
    for (int off = 32; off > 0; off >>= 1)
        v += __shfl_down(v, off, 64);
    if (lane == 0) out[0] = 1.f - v * (1.f / (float)N);
}

extern "C" void kernel_launch(void* const* d_in, const int* in_sizes, int n_in,
                              void* d_out, int out_size, void* d_ws, size_t ws_size,
                              hipStream_t stream) {
    const float* batch  = (const float*)d_in[0];
    const float* labels = (const float*)d_in[1];
    unsigned short* cid = (unsigned short*)d_ws;        // 8 KB
    float* slots = (float*)((char*)d_ws + 8192);        // 64 slots, 64 B apart
    fastap_cid_kernel<<<N / (4 * 4), BLOCK, 0, stream>>>(labels, cid, slots);
    fastap_row_kernel<<<N / 4, BLOCK, 0, stream>>>(batch, cid, slots);
    fastap_finalize<<<1, 64, 0, stream>>>(slots, (float*)d_out);
}